// Round 1
// baseline (245.258 us; speedup 1.0000x reference)
//
#include <hip/hip_runtime.h>

// Median-filter (k=22, REFLECT) + blend for NHWC (2,224,224,3) fp32.
// One 64-lane wave per output pixel. 484-element window held in registers
// (8 slots/lane, padded to 512 with +INF). Exact rank-242 selection via
// wave-uniform binary search on value (ballot+popcount counting), finished
// with duplicate-aware min-extraction. Entire input (1.2 MB) is L2-resident;
// kernel is compute-bound.

#define HH 224
#define WW 224
#define CHN 3
#define KK 22
#define PT 10
#define AREA (KK * KK)   // 484
#define RANK 242         // 1-indexed: (AREA-1)/2 zero-indexed == 242nd smallest

__device__ __forceinline__ int reflect224(int g) {
    // jnp.pad 'reflect': index -j -> j ; index (H-1)+j -> (H-1)-j. Single
    // reflection suffices since pad (10/11) < H.
    int a = abs(g);
    return min(a, 2 * (HH - 1) - a);
}

__global__ __launch_bounds__(256)
void median_blend_kernel(const float* __restrict__ in,
                         const float* __restrict__ blend,
                         float* __restrict__ out,
                         int total) {
    const int lane = threadIdx.x & 63;
    const int wid  = threadIdx.x >> 6;
    const int p = blockIdx.x * 4 + wid;       // one pixel per wave
    if (p >= total) return;                   // wave-uniform

    // p = ((b*H + y)*W + x)*C + c   (NHWC)
    const int c  = p % CHN;
    const int q  = p / CHN;
    const int xx = q % WW;
    const int q2 = q / WW;
    const int yy = q2 % HH;
    const int b  = q2 / HH;

    const float INF = __int_as_float(0x7f800000);

    // Load 8 window slots per lane; slots >= 484 become +INF sentinels.
    float v[8];
#pragma unroll
    for (int i = 0; i < 8; ++i) {
        int s  = lane + 64 * i;
        int se = min(s, AREA - 1);
        int row = se / KK;
        int col = se - row * KK;
        int gy = reflect224(yy - PT + row);
        int gx = reflect224(xx - PT + col);
        float val = in[((b * HH + gy) * WW + gx) * CHN + c];
        v[i] = (s < AREA) ? val : INF;
    }

    // Binary search on value: maintain #(v < lo) < RANK <= #(v < hi).
    // Input values are uniform in [0,1); INF sentinels never counted.
    float lo = 0.0f, hi = 1.0f;
    int clo = 0, chi = AREA;
    for (int it = 0; it < 24 && (chi - clo) > 4; ++it) {
        float t = 0.5f * (lo + hi);
        if (t <= lo || t >= hi) break;        // float saturation
        int cnt = 0;
#pragma unroll
        for (int i = 0; i < 8; ++i)
            cnt += __popcll(__ballot(v[i] < t));
        if (cnt >= RANK) { hi = t; chi = cnt; }
        else             { lo = t; clo = cnt; }
    }

    // Duplicate-aware min-extraction among candidates in [lo, hi).
    int r = RANK - clo;                       // rank within candidate set, >= 1
    float w[8];
#pragma unroll
    for (int i = 0; i < 8; ++i)
        w[i] = (v[i] >= lo && v[i] < hi) ? v[i] : INF;

    float med = 0.0f;
    for (int iter = 0; iter < AREA; ++iter) {
        float m = INF;
#pragma unroll
        for (int i = 0; i < 8; ++i) m = fminf(m, w[i]);
#pragma unroll
        for (int off = 32; off > 0; off >>= 1)
            m = fminf(m, __shfl_xor(m, off, 64));
        int ceq = 0;
#pragma unroll
        for (int i = 0; i < 8; ++i)
            ceq += __popcll(__ballot(w[i] == m));
        if (r <= ceq) { med = m; break; }
        r -= ceq;
#pragma unroll
        for (int i = 0; i < 8; ++i)
            if (w[i] == m) w[i] = INF;
    }

    // Center value x[b,yy,xx,c] lives at slot 230 = row 10, col 10
    // -> lane 38, reg 3  (38 + 64*3 == 230).
    float xc = __shfl(v[3], 38, 64);

    if (lane == 0) {
        float f = blend[0];
        out[p] = med + f * (xc - med);        // == filt + f*(x - filt)
    }
}

extern "C" void kernel_launch(void* const* d_in, const int* in_sizes, int n_in,
                              void* d_out, int out_size, void* d_ws, size_t ws_size,
                              hipStream_t stream) {
    const float* in    = (const float*)d_in[0];
    const float* blend = (const float*)d_in[1];
    float* out = (float*)d_out;

    int total = out_size;                      // 301056
    int nblocks = (total + 3) / 4;             // 4 waves (pixels) per block
    median_blend_kernel<<<nblocks, 256, 0, stream>>>(in, blend, out, total);
}